// Round 17
// baseline (319.574 us; speedup 1.0000x reference)
//
#include <hip/hip_runtime.h>
#include <cstdint>
#include <cstddef>

#define N 8192
#define F 64
#define NEMB 128
#define BI 16
#define BJ 256
#define NCHUNK 32
#define HALFCH 16
#define ROWSTR 560
#define LEAKY 0.01f

typedef __attribute__((ext_vector_type(8))) short bf16x8;
typedef __attribute__((ext_vector_type(4))) float f32x4;

__device__ __forceinline__ float wave_reduce_sum_f(float v){
  #pragma unroll
  for (int d = 32; d > 0; d >>= 1) v += __shfl_xor(v, d, 64);
  return v;
}
__device__ __forceinline__ int wave_reduce_sum_i(int v){
  #pragma unroll
  for (int d = 32; d > 0; d >>= 1) v += __shfl_xor(v, d, 64);
  return v;
}
__device__ __forceinline__ int wave_incl_scan_i(int v, int lane){
  #pragma unroll
  for (int d = 1; d < 64; d <<= 1){
    int u = __shfl_up(v, d, 64);
    if (lane >= d) v += u;
  }
  return v;
}
__device__ __forceinline__ unsigned short f2bf(float x){
  union { float f; unsigned u; } v; v.f = x;
  unsigned r = v.u + 0x7fff + ((v.u >> 16) & 1);
  return (unsigned short)(r >> 16);
}

// k_packh: blocks [0,N): adj row -> chunk-major masks + per-row-chunk counts +
// row totals. blocks [N, N+N/4): h = x@W^T + b; ssrc; sdst2x.
extern "C" __global__ void __launch_bounds__(256)
k_packh(const int* __restrict__ adj, unsigned short* __restrict__ bm,
        unsigned short* __restrict__ ccnt, int* __restrict__ rowtot,
        const float* __restrict__ x, const float* __restrict__ ww,
        const float* __restrict__ wb, const float* __restrict__ aw,
        float* __restrict__ h, float* __restrict__ ssrc, float* __restrict__ sdst2x){
  const int t = threadIdx.x;
  if (blockIdx.x < N){
    const int i = blockIdx.x;
    int total = 0;
    #pragma unroll
    for (int half = 0; half < 2; ++half){
      const int w = half*256 + t;           // word index 0..511
      const int4* p4 = (const int4*)(adj + (size_t)i*N + w*16);
      unsigned m = 0;
      #pragma unroll
      for (int k = 0; k < 4; ++k){
        int4 a = p4[k];
        m |= (unsigned)(a.x>0) << (k*4+0);
        m |= (unsigned)(a.y>0) << (k*4+1);
        m |= (unsigned)(a.z>0) << (k*4+2);
        m |= (unsigned)(a.w>0) << (k*4+3);
      }
      bm[((size_t)(w>>4)*N + i)*16 + (w&15)] = (unsigned short)m;
      const int pc = __popc(m);
      total += pc;
      int cs = pc;
      cs += __shfl_xor(cs, 1, 16);
      cs += __shfl_xor(cs, 2, 16);
      cs += __shfl_xor(cs, 4, 16);
      cs += __shfl_xor(cs, 8, 16);
      if ((t & 15) == 0) ccnt[(size_t)i*NCHUNK + (w>>4)] = (unsigned short)cs;
    }
    total = wave_reduce_sum_i(total);
    __shared__ int ws_[4];
    if ((t & 63) == 0) ws_[t >> 6] = total;
    __syncthreads();
    if (t == 0) rowtot[i] = ws_[0] + ws_[1] + ws_[2] + ws_[3];
  } else {
    const int w = t >> 6, lane = t & 63;
    __shared__ float xs[4][NEMB];
    const int n0 = (blockIdx.x - N) * 4;
    ((float2*)&xs[0][0])[t] = ((const float2*)(x + (size_t)n0 * NEMB))[t];
    __syncthreads();
    const int n = n0 + w;
    const float4* w4 = (const float4*)(ww + (size_t)lane * NEMB);
    const float4* x4 = (const float4*)&xs[w][0];
    float acc = wb[lane];
    #pragma unroll
    for (int k = 0; k < NEMB/4; ++k){
      float4 a = x4[k]; float4 b = w4[k];
      acc = fmaf(a.x, b.x, acc);
      acc = fmaf(a.y, b.y, acc);
      acc = fmaf(a.z, b.z, acc);
      acc = fmaf(a.w, b.w, acc);
    }
    h[(size_t)n * F + lane] = acc;
    float vs = wave_reduce_sum_f(acc * aw[lane]);
    float vd = wave_reduce_sum_f(acc * aw[F + lane]);
    if (lane == 0){ ssrc[n] = vs; sdst2x[n] = vd; sdst2x[n + N] = vd; }
  }
}

// k_tr: transpose h (fp32 [N][F]) -> ht (bf16 [F][N])
extern "C" __global__ void __launch_bounds__(256)
k_tr(const float* __restrict__ h, unsigned short* __restrict__ ht){
  __shared__ float tile[64][65];
  const int t = threadIdx.x;
  const int n0 = blockIdx.x * 64;
  #pragma unroll
  for (int s = 0; s < 4; ++s){
    const int r = s*16 + (t>>4);
    const int c = (t&15)*4;
    const float4 v = *(const float4*)(h + (size_t)(n0+r)*F + c);
    tile[r][c] = v.x; tile[r][c+1] = v.y; tile[r][c+2] = v.z; tile[r][c+3] = v.w;
  }
  __syncthreads();
  const int f = t >> 2, jq = t & 3;
  unsigned short buf[16];
  #pragma unroll
  for (int k = 0; k < 16; ++k) buf[k] = f2bf(tile[jq*16 + k][f]);
  *(uint4*)(ht + (size_t)f*N + n0 + jq*16)     = *(uint4*)&buf[0];
  *(uint4*)(ht + (size_t)f*N + n0 + jq*16 + 8) = *(uint4*)&buf[8];
}

// k_scan: exclusive scan of 8192 row totals -> base
extern "C" __global__ void __launch_bounds__(1024)
k_scan(const int* __restrict__ cnt, int* __restrict__ base){
  __shared__ int wsum[16];
  const int t = threadIdx.x, lane = t & 63, w = t >> 6;
  int4 aa = ((const int4*)cnt)[t * 2];
  int4 bb = ((const int4*)cnt)[t * 2 + 1];
  int v[8] = {aa.x, aa.y, aa.z, aa.w, bb.x, bb.y, bb.z, bb.w};
  int local = 0;
  #pragma unroll
  for (int k = 0; k < 8; ++k){ int tmp = v[k]; v[k] = local; local += tmp; }
  int inc = wave_incl_scan_i(local, lane);
  int wexcl = inc - local;
  if (lane == 63) wsum[w] = inc;
  __syncthreads();
  if (t == 0){
    int run = 0;
    #pragma unroll
    for (int k = 0; k < 16; ++k){ int tmp = wsum[k]; wsum[k] = run; run += tmp; }
  }
  __syncthreads();
  const int b0 = wsum[w] + wexcl;
  ((int4*)base)[t * 2]     = make_int4(b0 + v[0], b0 + v[1], b0 + v[2], b0 + v[3]);
  ((int4*)base)[t * 2 + 1] = make_int4(b0 + v[4], b0 + v[5], b0 + v[6], b0 + v[7]);
}

// k_main: 1024 independent blocks = (vid, half). 256 threads, 16 rows x 16 chunks.
// HOISTED bm loads + scans (registers, full unroll) -> produce starts at window
// loads; unconditional dummy-slot scatter; padded dbuf A-tile; reg B-prefetch
// pinned via sched_barrier; setprio around MFMA cluster.
extern "C" __global__ void __launch_bounds__(256, 4)
k_main(const unsigned short* __restrict__ bm, const unsigned short* __restrict__ ccnt,
       const int* __restrict__ base, const unsigned short* __restrict__ ht,
       const float* __restrict__ ssrc, const float* __restrict__ sdst2x,
       const float* __restrict__ abias,
       float* __restrict__ pnum, float* __restrict__ pden){
  __shared__ __attribute__((aligned(16))) char pt[2][16*ROWSTR]; // 17.5 KB dbuf A-tile
  __shared__ unsigned short ccum[BI][HALFCH];                    // chunk start ranks
  __shared__ int basel[BI];

  const int t = threadIdx.x, w = t >> 6, lane = t & 63;
  const int vid = blockIdx.x >> 1, half = blockIdx.x & 1;
  const int i0 = vid * BI;
  const int ch0 = half * HALFCH;

  if (t < BI) basel[t] = base[i0 + t];
  const int r = t >> 4, g = t & 15;         // produce roles
  // phase 0a: preload all 16 mask words for my (row, word-slot) into registers
  unsigned bmv[HALFCH];
  #pragma unroll
  for (int cc = 0; cc < HALFCH; ++cc)
    bmv[cc] = (unsigned)bm[((size_t)(ch0 + cc)*N + (i0 + r))*16 + g];
  // phase 0b: per-row within-row rank offsets for my 16 chunks (from ccnt)
  {
    int c = (int)ccnt[(size_t)(i0+r)*NCHUNK + ch0 + g];
    int pre = 0;
    if (half){
      pre = (int)ccnt[(size_t)(i0+r)*NCHUNK + g];
      #pragma unroll
      for (int d = 1; d < 16; d <<= 1) pre += __shfl_xor(pre, d, 16);
    }
    int inc = c;
    #pragma unroll
    for (int d = 1; d < 16; d <<= 1){ int u = __shfl_up(inc, d, 16); if (g >= d) inc += u; }
    ccum[r][g] = (unsigned short)(pre + inc - c);
  }
  // phase 0c: all 16 within-chunk scans up-front (registers, static indices)
  int qexv[HALFCH];
  #pragma unroll
  for (int cc = 0; cc < HALFCH; ++cc){
    const int c = __popc(bmv[cc]);
    int inc = c;
    #pragma unroll
    for (int d = 1; d < 16; d <<= 1){ int u = __shfl_up(inc, d, 16); if (g >= d) inc += u; }
    qexv[cc] = inc - c;
  }
  __syncthreads();

  const int fr = lane & 15, ks = lane >> 4; // mfma fragment roles
  const int fB = w*16 + fr;
  char* buf0 = pt[0];
  char* buf1 = pt[1];
  const float ab = abias[0];
  const int rowbase = basel[r];
  float dsum = 0.f;
  f32x4 acc = {0.f, 0.f, 0.f, 0.f};
  bf16x8 bregA[8], bregB[8];

#define PREFETCH(CH, BR) { \
    const unsigned short* hBp = ht + (size_t)fB*N + (CH)*BJ + ks*8; \
    _Pragma("unroll") \
    for (int kk = 0; kk < 8; ++kk) BR[kk] = *(const bf16x8*)(hBp + kk*32); \
    __builtin_amdgcn_sched_barrier(0); \
  }

  // produce: window loads + unconditional exp + unconditional select-address
  // scatter (active -> real slot, inactive -> per-thread dummy slot)
#define PRODUCE(CC, PB) { \
    const unsigned m = bmv[CC]; \
    const int c = __popc(m); \
    const int qex = qexv[CC]; \
    const int q0row = rowbase + (int)ccum[r][CC]; \
    const float* sdw = sdst2x + (q0row & (N - 1)) + qex; \
    const int ilo = q0row >> 13; \
    const float s_lo = ssrc[ilo]; \
    const float s_hi = ssrc[ilo + 1]; \
    const int krel = ((ilo + 1) << 13) - q0row - qex; \
    char* myrow = (PB) + r*ROWSTR; \
    *(uint4*)(myrow + g*32)      = make_uint4(0,0,0,0); \
    *(uint4*)(myrow + g*32 + 16) = make_uint4(0,0,0,0); \
    float wv[16]; \
    _Pragma("unroll") \
    for (int k = 0; k < 16; ++k) wv[k] = sdw[k]; \
    unsigned mc = m; \
    _Pragma("unroll") \
    for (int k = 0; k < 16; ++k){ \
      const float ss = (k >= krel) ? s_hi : s_lo; \
      float e = ss + wv[k] + ab; \
      e = (e > 0.f) ? e : LEAKY * e; \
      const float p = __expf(e); \
      const int pos = __ffs(mc) - 1; \
      const bool act = (k < c); \
      dsum += act ? p : 0.f; \
      const int off = act ? (g*32 + pos*2) : (512 + g*2); \
      *(unsigned short*)(myrow + off) = f2bf(p); \
      mc &= mc - 1; \
    } \
  }

#define MM(PB, BR) { \
    const char* aP = (PB) + fr*ROWSTR; \
    __builtin_amdgcn_s_setprio(1); \
    _Pragma("unroll") \
    for (int kk = 0; kk < 8; ++kk){ \
      bf16x8 av = *(const bf16x8*)(aP + kk*64 + ks*16); \
      acc = __builtin_amdgcn_mfma_f32_16x16x32_bf16(av, BR[kk], acc, 0, 0, 0); \
    } \
    __builtin_amdgcn_s_setprio(0); \
  }

  PREFETCH(ch0, bregA)
  PRODUCE(0, buf0)
  __syncthreads();
  #pragma unroll
  for (int cc = 0; cc < HALFCH; cc += 2){
    PREFETCH(ch0 + cc + 1, bregB)
    PRODUCE(cc + 1, buf1)
    MM(buf0, bregA)
    __syncthreads();
    if (cc + 2 < HALFCH){
      PREFETCH(ch0 + cc + 2, bregA)
      PRODUCE(cc + 2, buf0)
    }
    MM(buf1, bregB)
    __syncthreads();
  }
#undef PREFETCH
#undef PRODUCE
#undef MM

  // epilogue: partial denominators (produce roles) + partial numerators (mfma roles)
  #pragma unroll
  for (int d = 8; d > 0; d >>= 1) dsum += __shfl_xor(dsum, d, 16);
  if (g == 0) pden[(size_t)half*N + i0 + r] = dsum;
  #pragma unroll
  for (int reg = 0; reg < 4; ++reg){
    const int il = ks*4 + reg;
    pnum[(size_t)half*N*F + (size_t)(i0 + il)*F + fB] = acc[reg];
  }
}

// k_comb: out = elu((n0+n1)/(d0+d1))
extern "C" __global__ void __launch_bounds__(256)
k_comb(const float* __restrict__ pnum, const float* __restrict__ pden,
       float* __restrict__ out){
  const int idx = blockIdx.x * 256 + threadIdx.x;   // 0 .. N*F-1
  const int i = idx >> 6;
  const float dn = pden[i] + pden[N + i];
  const float nm = pnum[idx] + pnum[(size_t)N*F + idx];
  float v = (dn > 0.f) ? nm / dn : 0.f;
  out[idx] = (v > 0.f) ? v : (__expf(v) - 1.f);
}

extern "C" void kernel_launch(void* const* d_in, const int* in_sizes, int n_in,
                              void* d_out, int out_size, void* d_ws, size_t ws_size,
                              hipStream_t stream){
  const float* x   = (const float*)d_in[0];
  const int*   adj = (const int*)d_in[1];
  const float* ww  = (const float*)d_in[2];
  const float* wb  = (const float*)d_in[3];
  const float* aw  = (const float*)d_in[4];
  const float* ab  = (const float*)d_in[5];
  float* out = (float*)d_out;

  char* ws = (char*)d_ws;
  float*          h      = (float*)(ws);                       // 2 MB
  unsigned short* ht     = (unsigned short*)(ws + (2u<<20));   // 1 MB
  float*          ssrc   = (float*)(ws + (3u<<20));            // 32 KB
  float*          sdst2x = (float*)(ws + (3u<<20) + 32*1024);  // 64 KB
  int*            rowtot = (int*)(ws + (3u<<20) + 96*1024);    // 32 KB
  int*            base   = (int*)(ws + (3u<<20) + 128*1024);   // 32 KB
  unsigned short* ccnt   = (unsigned short*)(ws + (3u<<20) + 160*1024); // 512 KB
  unsigned short* bm     = (unsigned short*)(ws + (4u<<20));   // 8 MB
  float*          pnum   = (float*)(ws + (12u<<20));           // 4 MB
  float*          pden   = (float*)(ws + (16u<<20));           // 64 KB

  k_packh<<<N + N/4, 256, 0, stream>>>(adj, bm, ccnt, rowtot,
                                       x, ww, wb, aw, h, ssrc, sdst2x);
  k_tr  <<<N/64,   256, 0, stream>>>(h, ht);
  k_scan<<<1,     1024, 0, stream>>>(rowtot, base);
  k_main<<<2*(N/BI), 256, 0, stream>>>(bm, ccnt, base, ht, ssrc, sdst2x, ab, pnum, pden);
  k_comb<<<(N*F)/256, 256, 0, stream>>>(pnum, pden, out);
}

// Round 18
// 196.883 us; speedup vs baseline: 1.6232x; 1.6232x over previous
//
#include <hip/hip_runtime.h>
#include <cstdint>
#include <cstddef>

#define N 8192
#define F 64
#define NEMB 128
#define BI 16
#define BJ 256
#define NCHUNK 32
#define HALFCH 16
#define ROWSTR 560
#define LEAKY 0.01f

typedef __attribute__((ext_vector_type(8))) short bf16x8;
typedef __attribute__((ext_vector_type(4))) float f32x4;

__device__ __forceinline__ float wave_reduce_sum_f(float v){
  #pragma unroll
  for (int d = 32; d > 0; d >>= 1) v += __shfl_xor(v, d, 64);
  return v;
}
__device__ __forceinline__ int wave_reduce_sum_i(int v){
  #pragma unroll
  for (int d = 32; d > 0; d >>= 1) v += __shfl_xor(v, d, 64);
  return v;
}
__device__ __forceinline__ int wave_incl_scan_i(int v, int lane){
  #pragma unroll
  for (int d = 1; d < 64; d <<= 1){
    int u = __shfl_up(v, d, 64);
    if (lane >= d) v += u;
  }
  return v;
}
__device__ __forceinline__ unsigned short f2bf(float x){
  union { float f; unsigned u; } v; v.f = x;
  unsigned r = v.u + 0x7fff + ((v.u >> 16) & 1);
  return (unsigned short)(r >> 16);
}

// k_packh: blocks [0,N): adj row -> chunk-major masks + per-row-chunk counts +
// row totals. blocks [N, N+N/4): h = x@W^T + b; ssrc (with a_bias folded in);
// sdst2x.
extern "C" __global__ void __launch_bounds__(256)
k_packh(const int* __restrict__ adj, unsigned short* __restrict__ bm,
        unsigned short* __restrict__ ccnt, int* __restrict__ rowtot,
        const float* __restrict__ x, const float* __restrict__ ww,
        const float* __restrict__ wb, const float* __restrict__ aw,
        const float* __restrict__ abias,
        float* __restrict__ h, float* __restrict__ ssrc, float* __restrict__ sdst2x){
  const int t = threadIdx.x;
  if (blockIdx.x < N){
    const int i = blockIdx.x;
    int total = 0;
    #pragma unroll
    for (int half = 0; half < 2; ++half){
      const int w = half*256 + t;           // word index 0..511
      const int4* p4 = (const int4*)(adj + (size_t)i*N + w*16);
      unsigned m = 0;
      #pragma unroll
      for (int k = 0; k < 4; ++k){
        int4 a = p4[k];
        m |= (unsigned)(a.x>0) << (k*4+0);
        m |= (unsigned)(a.y>0) << (k*4+1);
        m |= (unsigned)(a.z>0) << (k*4+2);
        m |= (unsigned)(a.w>0) << (k*4+3);
      }
      bm[((size_t)(w>>4)*N + i)*16 + (w&15)] = (unsigned short)m;
      const int pc = __popc(m);
      total += pc;
      int cs = pc;
      cs += __shfl_xor(cs, 1, 16);
      cs += __shfl_xor(cs, 2, 16);
      cs += __shfl_xor(cs, 4, 16);
      cs += __shfl_xor(cs, 8, 16);
      if ((t & 15) == 0) ccnt[(size_t)i*NCHUNK + (w>>4)] = (unsigned short)cs;
    }
    total = wave_reduce_sum_i(total);
    __shared__ int ws_[4];
    if ((t & 63) == 0) ws_[t >> 6] = total;
    __syncthreads();
    if (t == 0) rowtot[i] = ws_[0] + ws_[1] + ws_[2] + ws_[3];
  } else {
    const int w = t >> 6, lane = t & 63;
    __shared__ float xs[4][NEMB];
    const int n0 = (blockIdx.x - N) * 4;
    ((float2*)&xs[0][0])[t] = ((const float2*)(x + (size_t)n0 * NEMB))[t];
    __syncthreads();
    const int n = n0 + w;
    const float4* w4 = (const float4*)(ww + (size_t)lane * NEMB);
    const float4* x4 = (const float4*)&xs[w][0];
    float acc = wb[lane];
    #pragma unroll
    for (int k = 0; k < NEMB/4; ++k){
      float4 a = x4[k]; float4 b = w4[k];
      acc = fmaf(a.x, b.x, acc);
      acc = fmaf(a.y, b.y, acc);
      acc = fmaf(a.z, b.z, acc);
      acc = fmaf(a.w, b.w, acc);
    }
    h[(size_t)n * F + lane] = acc;
    float vs = wave_reduce_sum_f(acc * aw[lane]);
    float vd = wave_reduce_sum_f(acc * aw[F + lane]);
    if (lane == 0){
      ssrc[n] = vs + abias[0];              // a_bias folded in
      sdst2x[n] = vd; sdst2x[n + N] = vd;
    }
  }
}

// k_tr: transpose h (fp32 [N][F]) -> ht (bf16 [F][N])
extern "C" __global__ void __launch_bounds__(256)
k_tr(const float* __restrict__ h, unsigned short* __restrict__ ht){
  __shared__ float tile[64][65];
  const int t = threadIdx.x;
  const int n0 = blockIdx.x * 64;
  #pragma unroll
  for (int s = 0; s < 4; ++s){
    const int r = s*16 + (t>>4);
    const int c = (t&15)*4;
    const float4 v = *(const float4*)(h + (size_t)(n0+r)*F + c);
    tile[r][c] = v.x; tile[r][c+1] = v.y; tile[r][c+2] = v.z; tile[r][c+3] = v.w;
  }
  __syncthreads();
  const int f = t >> 2, jq = t & 3;
  unsigned short buf[16];
  #pragma unroll
  for (int k = 0; k < 16; ++k) buf[k] = f2bf(tile[jq*16 + k][f]);
  *(uint4*)(ht + (size_t)f*N + n0 + jq*16)     = *(uint4*)&buf[0];
  *(uint4*)(ht + (size_t)f*N + n0 + jq*16 + 8) = *(uint4*)&buf[8];
}

// k_scan: exclusive scan of 8192 row totals -> base
extern "C" __global__ void __launch_bounds__(1024)
k_scan(const int* __restrict__ cnt, int* __restrict__ base){
  __shared__ int wsum[16];
  const int t = threadIdx.x, lane = t & 63, w = t >> 6;
  int4 aa = ((const int4*)cnt)[t * 2];
  int4 bb = ((const int4*)cnt)[t * 2 + 1];
  int v[8] = {aa.x, aa.y, aa.z, aa.w, bb.x, bb.y, bb.z, bb.w};
  int local = 0;
  #pragma unroll
  for (int k = 0; k < 8; ++k){ int tmp = v[k]; v[k] = local; local += tmp; }
  int inc = wave_incl_scan_i(local, lane);
  int wexcl = inc - local;
  if (lane == 63) wsum[w] = inc;
  __syncthreads();
  if (t == 0){
    int run = 0;
    #pragma unroll
    for (int k = 0; k < 16; ++k){ int tmp = wsum[k]; wsum[k] = run; run += tmp; }
  }
  __syncthreads();
  const int b0 = wsum[w] + wexcl;
  ((int4*)base)[t * 2]     = make_int4(b0 + v[0], b0 + v[1], b0 + v[2], b0 + v[3]);
  ((int4*)base)[t * 2 + 1] = make_int4(b0 + v[4], b0 + v[5], b0 + v[6], b0 + v[7]);
}

// k_main: 1024 independent blocks = (vid, half). 256 threads, 16 rows x 16 chunks.
// Depth-1 pipelined produce: PLOAD (scan + issue window/ssrc loads + zero-fill)
// BEFORE MM, PSTORE (exp + scatter) AFTER MM; bm words rotated one chunk ahead
// in scalar regs; unconditional dummy-slot scatter; padded dbuf A-tile;
// reg B-prefetch pinned via sched_barrier; setprio around MFMA cluster.
extern "C" __global__ void __launch_bounds__(256, 4)
k_main(const unsigned short* __restrict__ bm, const unsigned short* __restrict__ ccnt,
       const int* __restrict__ base, const unsigned short* __restrict__ ht,
       const float* __restrict__ ssrc, const float* __restrict__ sdst2x,
       float* __restrict__ pnum, float* __restrict__ pden){
  __shared__ __attribute__((aligned(16))) char pt[2][16*ROWSTR]; // 17.5 KB dbuf A-tile
  __shared__ unsigned short ccum[BI][HALFCH];                    // chunk start ranks
  __shared__ int basel[BI];

  const int t = threadIdx.x, w = t >> 6, lane = t & 63;
  const int vid = blockIdx.x >> 1, half = blockIdx.x & 1;
  const int i0 = vid * BI;
  const int ch0 = half * HALFCH;

  if (t < BI) basel[t] = base[i0 + t];
  const int r = t >> 4, g = t & 15;         // produce roles
  // phase 0: per-row within-row rank offsets for my 16 chunks (from ccnt)
  {
    int c = (int)ccnt[(size_t)(i0+r)*NCHUNK + ch0 + g];
    int pre = 0;
    if (half){
      pre = (int)ccnt[(size_t)(i0+r)*NCHUNK + g];
      #pragma unroll
      for (int d = 1; d < 16; d <<= 1) pre += __shfl_xor(pre, d, 16);
    }
    int inc = c;
    #pragma unroll
    for (int d = 1; d < 16; d <<= 1){ int u = __shfl_up(inc, d, 16); if (g >= d) inc += u; }
    ccum[r][g] = (unsigned short)(pre + inc - c);
  }
  __syncthreads();

  const int fr = lane & 15, ks = lane >> 4; // mfma fragment roles
  const int fB = w*16 + fr;
  char* buf0 = pt[0];
  char* buf1 = pt[1];
  const int rowbase = basel[r];
  float dsum = 0.f;
  f32x4 acc = {0.f, 0.f, 0.f, 0.f};
  bf16x8 bregA[8], bregB[8];

#define BMLD(CC) ((unsigned)bm[((size_t)(ch0 + (CC))*N + (i0 + r))*16 + g])

#define PREFETCH(CH, BR) { \
    const unsigned short* hBp = ht + (size_t)fB*N + (CH)*BJ + ks*8; \
    _Pragma("unroll") \
    for (int kk = 0; kk < 8; ++kk) BR[kk] = *(const bf16x8*)(hBp + kk*32); \
    __builtin_amdgcn_sched_barrier(0); \
  }

  // PLOAD: scan + addresses + issue window/ssrc loads + zero-fill target rows.
  // Declares locals (c, krel, s_lo, s_hi, wv) consumed by PSTORE in same scope.
#define PLOAD(MV, CC, PB) \
    const int c = __popc(MV); \
    int inc_ = c; \
    _Pragma("unroll") \
    for (int d = 1; d < 16; d <<= 1){ int u = __shfl_up(inc_, d, 16); if (g >= d) inc_ += u; } \
    const int qex = inc_ - c; \
    const int q0row = rowbase + (int)ccum[r][CC]; \
    const float* sdw = sdst2x + (q0row & (N - 1)) + qex; \
    const int ilo = q0row >> 13; \
    const float s_lo = ssrc[ilo]; \
    const float s_hi = ssrc[ilo + 1]; \
    const int krel = ((ilo + 1) << 13) - q0row - qex; \
    char* myrow = (PB) + r*ROWSTR; \
    *(uint4*)(myrow + g*32)      = make_uint4(0,0,0,0); \
    *(uint4*)(myrow + g*32 + 16) = make_uint4(0,0,0,0); \
    float wv[16]; \
    _Pragma("unroll") \
    for (int k = 0; k < 16; ++k) wv[k] = sdw[k];

  // PSTORE: exp + unconditional select-address scatter
#define PSTORE(MV) { \
    unsigned mc = (MV); \
    _Pragma("unroll") \
    for (int k = 0; k < 16; ++k){ \
      const float ss = (k >= krel) ? s_hi : s_lo; \
      float e = ss + wv[k]; \
      e = (e > 0.f) ? e : LEAKY * e; \
      const float p = __expf(e); \
      const int pos = __ffs(mc) - 1; \
      const bool act = (k < c); \
      dsum += act ? p : 0.f; \
      const int off = act ? (g*32 + pos*2) : (512 + g*2); \
      *(unsigned short*)(myrow + off) = f2bf(p); \
      mc &= mc - 1; \
    } \
  }

#define MM(PB, BR) { \
    const char* aP = (PB) + fr*ROWSTR; \
    __builtin_amdgcn_s_setprio(1); \
    _Pragma("unroll") \
    for (int kk = 0; kk < 8; ++kk){ \
      bf16x8 av = *(const bf16x8*)(aP + kk*64 + ks*16); \
      acc = __builtin_amdgcn_mfma_f32_16x16x32_bf16(av, BR[kk], acc, 0, 0, 0); \
    } \
    __builtin_amdgcn_s_setprio(0); \
  }

  // prologue: chunk 0 produced (no MM to hide under); bm for chunk 1 in flight
  unsigned mA = 0, mB = 0;
  {
    const unsigned m0 = BMLD(0);
    mA = BMLD(1);
    PREFETCH(ch0, bregA)
    PLOAD(m0, 0, buf0)
    PSTORE(m0)
  }
  __syncthreads();

  for (int cc = 0; cc < HALFCH; cc += 2){
    { // half A: pipeline produce(cc+1)->buf1 around MM(buf0)
      PLOAD(mA, cc + 1, buf1)
      if (cc + 2 < HALFCH) mB = BMLD(cc + 2);
      PREFETCH(ch0 + cc + 1, bregB)
      MM(buf0, bregA)
      PSTORE(mA)
    }
    __syncthreads();
    if (cc + 2 < HALFCH){ // half B: produce(cc+2)->buf0 around MM(buf1)
      PLOAD(mB, cc + 2, buf0)
      if (cc + 3 < HALFCH) mA = BMLD(cc + 3);
      PREFETCH(ch0 + cc + 2, bregA)
      MM(buf1, bregB)
      PSTORE(mB)
    } else {
      MM(buf1, bregB)
    }
    __syncthreads();
  }
#undef BMLD
#undef PREFETCH
#undef PLOAD
#undef PSTORE
#undef MM

  // epilogue: partial denominators (produce roles) + partial numerators (mfma roles)
  #pragma unroll
  for (int d = 8; d > 0; d >>= 1) dsum += __shfl_xor(dsum, d, 16);
  if (g == 0) pden[(size_t)half*N + i0 + r] = dsum;
  #pragma unroll
  for (int reg = 0; reg < 4; ++reg){
    const int il = ks*4 + reg;
    pnum[(size_t)half*N*F + (size_t)(i0 + il)*F + fB] = acc[reg];
  }
}

// k_comb: out = elu((n0+n1)/(d0+d1))
extern "C" __global__ void __launch_bounds__(256)
k_comb(const float* __restrict__ pnum, const float* __restrict__ pden,
       float* __restrict__ out){
  const int idx = blockIdx.x * 256 + threadIdx.x;   // 0 .. N*F-1
  const int i = idx >> 6;
  const float dn = pden[i] + pden[N + i];
  const float nm = pnum[idx] + pnum[(size_t)N*F + idx];
  float v = (dn > 0.f) ? nm / dn : 0.f;
  out[idx] = (v > 0.f) ? v : (__expf(v) - 1.f);
}

extern "C" void kernel_launch(void* const* d_in, const int* in_sizes, int n_in,
                              void* d_out, int out_size, void* d_ws, size_t ws_size,
                              hipStream_t stream){
  const float* x   = (const float*)d_in[0];
  const int*   adj = (const int*)d_in[1];
  const float* ww  = (const float*)d_in[2];
  const float* wb  = (const float*)d_in[3];
  const float* aw  = (const float*)d_in[4];
  const float* ab  = (const float*)d_in[5];
  float* out = (float*)d_out;

  char* ws = (char*)d_ws;
  float*          h      = (float*)(ws);                       // 2 MB
  unsigned short* ht     = (unsigned short*)(ws + (2u<<20));   // 1 MB
  float*          ssrc   = (float*)(ws + (3u<<20));            // 32 KB
  float*          sdst2x = (float*)(ws + (3u<<20) + 32*1024);  // 64 KB
  int*            rowtot = (int*)(ws + (3u<<20) + 96*1024);    // 32 KB
  int*            base   = (int*)(ws + (3u<<20) + 128*1024);   // 32 KB
  unsigned short* ccnt   = (unsigned short*)(ws + (3u<<20) + 160*1024); // 512 KB
  unsigned short* bm     = (unsigned short*)(ws + (4u<<20));   // 8 MB
  float*          pnum   = (float*)(ws + (12u<<20));           // 4 MB
  float*          pden   = (float*)(ws + (16u<<20));           // 64 KB

  k_packh<<<N + N/4, 256, 0, stream>>>(adj, bm, ccnt, rowtot,
                                       x, ww, wb, aw, ab, h, ssrc, sdst2x);
  k_tr  <<<N/64,   256, 0, stream>>>(h, ht);
  k_scan<<<1,     1024, 0, stream>>>(rowtot, base);
  k_main<<<2*(N/BI), 256, 0, stream>>>(bm, ccnt, base, ht, ssrc, sdst2x, pnum, pden);
  k_comb<<<(N*F)/256, 256, 0, stream>>>(pnum, pden, out);
}

// Round 19
// 164.323 us; speedup vs baseline: 1.9448x; 1.1982x over previous
//
#include <hip/hip_runtime.h>
#include <cstdint>
#include <cstddef>

#define N 8192
#define F 64
#define NEMB 128
#define BI 16
#define BJ 256
#define NCHUNK 32
#define HALFCH 16
#define ROWSTR 560
#define LEAKY 0.01f

typedef __attribute__((ext_vector_type(8))) short bf16x8;
typedef __attribute__((ext_vector_type(4))) float f32x4;

__device__ __forceinline__ float wave_reduce_sum_f(float v){
  #pragma unroll
  for (int d = 32; d > 0; d >>= 1) v += __shfl_xor(v, d, 64);
  return v;
}
__device__ __forceinline__ int wave_reduce_sum_i(int v){
  #pragma unroll
  for (int d = 32; d > 0; d >>= 1) v += __shfl_xor(v, d, 64);
  return v;
}
__device__ __forceinline__ int wave_incl_scan_i(int v, int lane){
  #pragma unroll
  for (int d = 1; d < 64; d <<= 1){
    int u = __shfl_up(v, d, 64);
    if (lane >= d) v += u;
  }
  return v;
}
__device__ __forceinline__ unsigned short f2bf(float x){
  union { float f; unsigned u; } v; v.f = x;
  unsigned r = v.u + 0x7fff + ((v.u >> 16) & 1);
  return (unsigned short)(r >> 16);
}

// k_packh: blocks [0,N): adj row -> chunk-major masks + per-row-chunk counts +
// row totals. blocks [N, N+N/4): h = x@W^T + b; ssrc (a_bias folded); sdst2x.
extern "C" __global__ void __launch_bounds__(256)
k_packh(const int* __restrict__ adj, unsigned short* __restrict__ bm,
        unsigned short* __restrict__ ccnt, int* __restrict__ rowtot,
        const float* __restrict__ x, const float* __restrict__ ww,
        const float* __restrict__ wb, const float* __restrict__ aw,
        const float* __restrict__ abias,
        float* __restrict__ h, float* __restrict__ ssrc, float* __restrict__ sdst2x){
  const int t = threadIdx.x;
  if (blockIdx.x < N){
    const int i = blockIdx.x;
    int total = 0;
    #pragma unroll
    for (int half = 0; half < 2; ++half){
      const int w = half*256 + t;           // word index 0..511
      const int4* p4 = (const int4*)(adj + (size_t)i*N + w*16);
      unsigned m = 0;
      #pragma unroll
      for (int k = 0; k < 4; ++k){
        int4 a = p4[k];
        m |= (unsigned)(a.x>0) << (k*4+0);
        m |= (unsigned)(a.y>0) << (k*4+1);
        m |= (unsigned)(a.z>0) << (k*4+2);
        m |= (unsigned)(a.w>0) << (k*4+3);
      }
      bm[((size_t)(w>>4)*N + i)*16 + (w&15)] = (unsigned short)m;
      const int pc = __popc(m);
      total += pc;
      int cs = pc;
      cs += __shfl_xor(cs, 1, 16);
      cs += __shfl_xor(cs, 2, 16);
      cs += __shfl_xor(cs, 4, 16);
      cs += __shfl_xor(cs, 8, 16);
      if ((t & 15) == 0) ccnt[(size_t)i*NCHUNK + (w>>4)] = (unsigned short)cs;
    }
    total = wave_reduce_sum_i(total);
    __shared__ int ws_[4];
    if ((t & 63) == 0) ws_[t >> 6] = total;
    __syncthreads();
    if (t == 0) rowtot[i] = ws_[0] + ws_[1] + ws_[2] + ws_[3];
  } else {
    const int w = t >> 6, lane = t & 63;
    __shared__ float xs[4][NEMB];
    const int n0 = (blockIdx.x - N) * 4;
    ((float2*)&xs[0][0])[t] = ((const float2*)(x + (size_t)n0 * NEMB))[t];
    __syncthreads();
    const int n = n0 + w;
    const float4* w4 = (const float4*)(ww + (size_t)lane * NEMB);
    const float4* x4 = (const float4*)&xs[w][0];
    float acc = wb[lane];
    #pragma unroll
    for (int k = 0; k < NEMB/4; ++k){
      float4 a = x4[k]; float4 b = w4[k];
      acc = fmaf(a.x, b.x, acc);
      acc = fmaf(a.y, b.y, acc);
      acc = fmaf(a.z, b.z, acc);
      acc = fmaf(a.w, b.w, acc);
    }
    h[(size_t)n * F + lane] = acc;
    float vs = wave_reduce_sum_f(acc * aw[lane]);
    float vd = wave_reduce_sum_f(acc * aw[F + lane]);
    if (lane == 0){
      ssrc[n] = vs + abias[0];              // a_bias folded in
      sdst2x[n] = vd; sdst2x[n + N] = vd;
    }
  }
}

// k_tr: transpose h (fp32 [N][F]) -> ht (bf16 [F][N])
extern "C" __global__ void __launch_bounds__(256)
k_tr(const float* __restrict__ h, unsigned short* __restrict__ ht){
  __shared__ float tile[64][65];
  const int t = threadIdx.x;
  const int n0 = blockIdx.x * 64;
  #pragma unroll
  for (int s = 0; s < 4; ++s){
    const int r = s*16 + (t>>4);
    const int c = (t&15)*4;
    const float4 v = *(const float4*)(h + (size_t)(n0+r)*F + c);
    tile[r][c] = v.x; tile[r][c+1] = v.y; tile[r][c+2] = v.z; tile[r][c+3] = v.w;
  }
  __syncthreads();
  const int f = t >> 2, jq = t & 3;
  unsigned short buf[16];
  #pragma unroll
  for (int k = 0; k < 16; ++k) buf[k] = f2bf(tile[jq*16 + k][f]);
  *(uint4*)(ht + (size_t)f*N + n0 + jq*16)     = *(uint4*)&buf[0];
  *(uint4*)(ht + (size_t)f*N + n0 + jq*16 + 8) = *(uint4*)&buf[8];
}

// k_scan: exclusive scan of 8192 row totals -> base
extern "C" __global__ void __launch_bounds__(1024)
k_scan(const int* __restrict__ cnt, int* __restrict__ base){
  __shared__ int wsum[16];
  const int t = threadIdx.x, lane = t & 63, w = t >> 6;
  int4 aa = ((const int4*)cnt)[t * 2];
  int4 bb = ((const int4*)cnt)[t * 2 + 1];
  int v[8] = {aa.x, aa.y, aa.z, aa.w, bb.x, bb.y, bb.z, bb.w};
  int local = 0;
  #pragma unroll
  for (int k = 0; k < 8; ++k){ int tmp = v[k]; v[k] = local; local += tmp; }
  int inc = wave_incl_scan_i(local, lane);
  int wexcl = inc - local;
  if (lane == 63) wsum[w] = inc;
  __syncthreads();
  if (t == 0){
    int run = 0;
    #pragma unroll
    for (int k = 0; k < 16; ++k){ int tmp = wsum[k]; wsum[k] = run; run += tmp; }
  }
  __syncthreads();
  const int b0 = wsum[w] + wexcl;
  ((int4*)base)[t * 2]     = make_int4(b0 + v[0], b0 + v[1], b0 + v[2], b0 + v[3]);
  ((int4*)base)[t * 2 + 1] = make_int4(b0 + v[4], b0 + v[5], b0 + v[6], b0 + v[7]);
}

// k_main: 1024 independent blocks = (vid, half). 256 threads, 16 rows x 16 chunks.
// R16 structure (produce self-contained) with DUAL 8-bit chains inside produce:
// low/high byte masks get independent ffs chains, window arrays, denominators.
extern "C" __global__ void __launch_bounds__(256, 4)
k_main(const unsigned short* __restrict__ bm, const unsigned short* __restrict__ ccnt,
       const int* __restrict__ base, const unsigned short* __restrict__ ht,
       const float* __restrict__ ssrc, const float* __restrict__ sdst2x,
       float* __restrict__ pnum, float* __restrict__ pden){
  __shared__ __attribute__((aligned(16))) char pt[2][16*ROWSTR]; // 17.5 KB dbuf A-tile
  __shared__ unsigned short ccum[BI][HALFCH];                    // chunk start ranks
  __shared__ int basel[BI];

  const int t = threadIdx.x, w = t >> 6, lane = t & 63;
  const int vid = blockIdx.x >> 1, half = blockIdx.x & 1;
  const int i0 = vid * BI;
  const int ch0 = half * HALFCH;

  if (t < BI) basel[t] = base[i0 + t];
  const int r = t >> 4, g = t & 15;         // produce roles
  // phase 0: per-row within-row rank offsets for my 16 chunks (from ccnt)
  {
    int c = (int)ccnt[(size_t)(i0+r)*NCHUNK + ch0 + g];
    int pre = 0;
    if (half){
      pre = (int)ccnt[(size_t)(i0+r)*NCHUNK + g];
      #pragma unroll
      for (int d = 1; d < 16; d <<= 1) pre += __shfl_xor(pre, d, 16);
    }
    int inc = c;
    #pragma unroll
    for (int d = 1; d < 16; d <<= 1){ int u = __shfl_up(inc, d, 16); if (g >= d) inc += u; }
    ccum[r][g] = (unsigned short)(pre + inc - c);
  }
  __syncthreads();

  const int fr = lane & 15, ks = lane >> 4; // mfma fragment roles
  const int fB = w*16 + fr;
  char* buf0 = pt[0];
  char* buf1 = pt[1];
  const int rowbase = basel[r];
  float dsum = 0.f;
  f32x4 acc = {0.f, 0.f, 0.f, 0.f};
  bf16x8 bregA[8], bregB[8];

#define PREFETCH(CH, BR) { \
    const unsigned short* hBp = ht + (size_t)fB*N + (CH)*BJ + ks*8; \
    _Pragma("unroll") \
    for (int kk = 0; kk < 8; ++kk) BR[kk] = *(const bf16x8*)(hBp + kk*32); \
    __builtin_amdgcn_sched_barrier(0); \
  }

  // produce: dual 8-bit chains (low/high byte of mask word) — independent
  // window arrays, ffs chains, and denominator partials; unconditional
  // select-address scatter (active -> real slot, inactive -> dummy slot)
#define PRODUCE(CC, PB) { \
    const unsigned m = (unsigned)bm[((size_t)(ch0 + (CC))*N + (i0 + r))*16 + g]; \
    const unsigned mlo = m & 0xffu, mhi = m >> 8; \
    const int clo = __popc(mlo), chi = __popc(mhi); \
    const int c = clo + chi; \
    int inc = c; \
    _Pragma("unroll") \
    for (int d = 1; d < 16; d <<= 1){ int u = __shfl_up(inc, d, 16); if (g >= d) inc += u; } \
    const int qex = inc - c; \
    const int q0row = rowbase + (int)ccum[r][CC]; \
    const float* sdw = sdst2x + (q0row & (N - 1)) + qex; \
    const int ilo = q0row >> 13; \
    const float s_lo = ssrc[ilo]; \
    const float s_hi = ssrc[ilo + 1]; \
    const int krel = ((ilo + 1) << 13) - q0row - qex; \
    char* myrow = (PB) + r*ROWSTR; \
    *(uint4*)(myrow + g*32)      = make_uint4(0,0,0,0); \
    *(uint4*)(myrow + g*32 + 16) = make_uint4(0,0,0,0); \
    float wvlo[8], wvhi[8]; \
    const float* sdh = sdw + clo; \
    _Pragma("unroll") \
    for (int k = 0; k < 8; ++k){ wvlo[k] = sdw[k]; wvhi[k] = sdh[k]; } \
    float dlo = 0.f, dhi = 0.f; \
    unsigned mcl = mlo, mch = mhi; \
    _Pragma("unroll") \
    for (int k = 0; k < 8; ++k){ \
      { \
        const float ss = (k >= krel) ? s_hi : s_lo; \
        float e = ss + wvlo[k]; \
        e = (e > 0.f) ? e : LEAKY * e; \
        const float p = __expf(e); \
        const int pos = __ffs(mcl) - 1; \
        const bool act = (k < clo); \
        dlo += act ? p : 0.f; \
        const int off = act ? (g*32 + pos*2) : (512 + g*2); \
        *(unsigned short*)(myrow + off) = f2bf(p); \
        mcl &= mcl - 1; \
      } \
      { \
        const int kg = clo + k; \
        const float ss = (kg >= krel) ? s_hi : s_lo; \
        float e = ss + wvhi[k]; \
        e = (e > 0.f) ? e : LEAKY * e; \
        const float p = __expf(e); \
        const int pos = __ffs(mch) + 7; \
        const bool act = (k < chi); \
        dhi += act ? p : 0.f; \
        const int off = act ? (g*32 + pos*2) : (512 + g*2); \
        *(unsigned short*)(myrow + off) = f2bf(p); \
        mch &= mch - 1; \
      } \
    } \
    dsum += dlo + dhi; \
  }

#define MM(PB, BR) { \
    const char* aP = (PB) + fr*ROWSTR; \
    __builtin_amdgcn_s_setprio(1); \
    _Pragma("unroll") \
    for (int kk = 0; kk < 8; ++kk){ \
      bf16x8 av = *(const bf16x8*)(aP + kk*64 + ks*16); \
      acc = __builtin_amdgcn_mfma_f32_16x16x32_bf16(av, BR[kk], acc, 0, 0, 0); \
    } \
    __builtin_amdgcn_s_setprio(0); \
  }

  PREFETCH(ch0, bregA)
  PRODUCE(0, buf0)
  __syncthreads();
  for (int cc = 0; cc < HALFCH; cc += 2){
    PREFETCH(ch0 + cc + 1, bregB)
    PRODUCE(cc + 1, buf1)
    MM(buf0, bregA)
    __syncthreads();
    if (cc + 2 < HALFCH){
      PREFETCH(ch0 + cc + 2, bregA)
      PRODUCE(cc + 2, buf0)
    }
    MM(buf1, bregB)
    __syncthreads();
  }
#undef PREFETCH
#undef PRODUCE
#undef MM

  // epilogue: partial denominators (produce roles) + partial numerators (mfma roles)
  #pragma unroll
  for (int d = 8; d > 0; d >>= 1) dsum += __shfl_xor(dsum, d, 16);
  if (g == 0) pden[(size_t)half*N + i0 + r] = dsum;
  #pragma unroll
  for (int reg = 0; reg < 4; ++reg){
    const int il = ks*4 + reg;
    pnum[(size_t)half*N*F + (size_t)(i0 + il)*F + fB] = acc[reg];
  }
}

// k_comb: out = elu((n0+n1)/(d0+d1))
extern "C" __global__ void __launch_bounds__(256)
k_comb(const float* __restrict__ pnum, const float* __restrict__ pden,
       float* __restrict__ out){
  const int idx = blockIdx.x * 256 + threadIdx.x;   // 0 .. N*F-1
  const int i = idx >> 6;
  const float dn = pden[i] + pden[N + i];
  const float nm = pnum[idx] + pnum[(size_t)N*F + idx];
  float v = (dn > 0.f) ? nm / dn : 0.f;
  out[idx] = (v > 0.f) ? v : (__expf(v) - 1.f);
}

extern "C" void kernel_launch(void* const* d_in, const int* in_sizes, int n_in,
                              void* d_out, int out_size, void* d_ws, size_t ws_size,
                              hipStream_t stream){
  const float* x   = (const float*)d_in[0];
  const int*   adj = (const int*)d_in[1];
  const float* ww  = (const float*)d_in[2];
  const float* wb  = (const float*)d_in[3];
  const float* aw  = (const float*)d_in[4];
  const float* ab  = (const float*)d_in[5];
  float* out = (float*)d_out;

  char* ws = (char*)d_ws;
  float*          h      = (float*)(ws);                       // 2 MB
  unsigned short* ht     = (unsigned short*)(ws + (2u<<20));   // 1 MB
  float*          ssrc   = (float*)(ws + (3u<<20));            // 32 KB
  float*          sdst2x = (float*)(ws + (3u<<20) + 32*1024);  // 64 KB
  int*            rowtot = (int*)(ws + (3u<<20) + 96*1024);    // 32 KB
  int*            base   = (int*)(ws + (3u<<20) + 128*1024);   // 32 KB
  unsigned short* ccnt   = (unsigned short*)(ws + (3u<<20) + 160*1024); // 512 KB
  unsigned short* bm     = (unsigned short*)(ws + (4u<<20));   // 8 MB
  float*          pnum   = (float*)(ws + (12u<<20));           // 4 MB
  float*          pden   = (float*)(ws + (16u<<20));           // 64 KB

  k_packh<<<N + N/4, 256, 0, stream>>>(adj, bm, ccnt, rowtot,
                                       x, ww, wb, aw, ab, h, ssrc, sdst2x);
  k_tr  <<<N/64,   256, 0, stream>>>(h, ht);
  k_scan<<<1,     1024, 0, stream>>>(rowtot, base);
  k_main<<<2*(N/BI), 256, 0, stream>>>(bm, ccnt, base, ht, ssrc, sdst2x, pnum, pden);
  k_comb<<<(N*F)/256, 256, 0, stream>>>(pnum, pden, out);
}

// Round 20
// 162.478 us; speedup vs baseline: 1.9669x; 1.0114x over previous
//
#include <hip/hip_runtime.h>
#include <cstdint>
#include <cstddef>

#define N 8192
#define F 64
#define NEMB 128
#define BI 16
#define BJ 256
#define NCHUNK 32
#define HALFCH 16
#define ROWSTR 560
#define LEAKY 0.01f

typedef __attribute__((ext_vector_type(8))) short bf16x8;
typedef __attribute__((ext_vector_type(4))) float f32x4;

__device__ __forceinline__ float wave_reduce_sum_f(float v){
  #pragma unroll
  for (int d = 32; d > 0; d >>= 1) v += __shfl_xor(v, d, 64);
  return v;
}
__device__ __forceinline__ int wave_reduce_sum_i(int v){
  #pragma unroll
  for (int d = 32; d > 0; d >>= 1) v += __shfl_xor(v, d, 64);
  return v;
}
__device__ __forceinline__ int wave_incl_scan_i(int v, int lane){
  #pragma unroll
  for (int d = 1; d < 64; d <<= 1){
    int u = __shfl_up(v, d, 64);
    if (lane >= d) v += u;
  }
  return v;
}
__device__ __forceinline__ unsigned short f2bf(float x){
  union { float f; unsigned u; } v; v.f = x;
  unsigned r = v.u + 0x7fff + ((v.u >> 16) & 1);
  return (unsigned short)(r >> 16);
}

// k_packh: blocks [0,N): adj row -> BLOCK-MAJOR masks bm[vid][ch][(i&15)*16+g]
// + per-row-chunk counts + row totals. blocks [N, N+N/4): h = x@W^T + b;
// ssrc (a_bias folded); sdst2x.
extern "C" __global__ void __launch_bounds__(256)
k_packh(const int* __restrict__ adj, unsigned short* __restrict__ bm,
        unsigned short* __restrict__ ccnt, int* __restrict__ rowtot,
        const float* __restrict__ x, const float* __restrict__ ww,
        const float* __restrict__ wb, const float* __restrict__ aw,
        const float* __restrict__ abias,
        float* __restrict__ h, float* __restrict__ ssrc, float* __restrict__ sdst2x){
  const int t = threadIdx.x;
  if (blockIdx.x < N){
    const int i = blockIdx.x;
    int total = 0;
    #pragma unroll
    for (int half = 0; half < 2; ++half){
      const int w = half*256 + t;           // word index 0..511
      const int4* p4 = (const int4*)(adj + (size_t)i*N + w*16);
      unsigned m = 0;
      #pragma unroll
      for (int k = 0; k < 4; ++k){
        int4 a = p4[k];
        m |= (unsigned)(a.x>0) << (k*4+0);
        m |= (unsigned)(a.y>0) << (k*4+1);
        m |= (unsigned)(a.z>0) << (k*4+2);
        m |= (unsigned)(a.w>0) << (k*4+3);
      }
      // block-major: [i>>4][w>>4][(i&15)*16 + (w&15)]
      bm[((size_t)(i >> 4)*NCHUNK + (w >> 4))*256 + (i & 15)*16 + (w & 15)] =
          (unsigned short)m;
      const int pc = __popc(m);
      total += pc;
      int cs = pc;
      cs += __shfl_xor(cs, 1, 16);
      cs += __shfl_xor(cs, 2, 16);
      cs += __shfl_xor(cs, 4, 16);
      cs += __shfl_xor(cs, 8, 16);
      if ((t & 15) == 0) ccnt[(size_t)i*NCHUNK + (w>>4)] = (unsigned short)cs;
    }
    total = wave_reduce_sum_i(total);
    __shared__ int ws_[4];
    if ((t & 63) == 0) ws_[t >> 6] = total;
    __syncthreads();
    if (t == 0) rowtot[i] = ws_[0] + ws_[1] + ws_[2] + ws_[3];
  } else {
    const int w = t >> 6, lane = t & 63;
    __shared__ float xs[4][NEMB];
    const int n0 = (blockIdx.x - N) * 4;
    ((float2*)&xs[0][0])[t] = ((const float2*)(x + (size_t)n0 * NEMB))[t];
    __syncthreads();
    const int n = n0 + w;
    const float4* w4 = (const float4*)(ww + (size_t)lane * NEMB);
    const float4* x4 = (const float4*)&xs[w][0];
    float acc = wb[lane];
    #pragma unroll
    for (int k = 0; k < NEMB/4; ++k){
      float4 a = x4[k]; float4 b = w4[k];
      acc = fmaf(a.x, b.x, acc);
      acc = fmaf(a.y, b.y, acc);
      acc = fmaf(a.z, b.z, acc);
      acc = fmaf(a.w, b.w, acc);
    }
    h[(size_t)n * F + lane] = acc;
    float vs = wave_reduce_sum_f(acc * aw[lane]);
    float vd = wave_reduce_sum_f(acc * aw[F + lane]);
    if (lane == 0){
      ssrc[n] = vs + abias[0];              // a_bias folded in
      sdst2x[n] = vd; sdst2x[n + N] = vd;
    }
  }
}

// k_tr: transpose h (fp32 [N][F]) -> ht (bf16 [F][N])
extern "C" __global__ void __launch_bounds__(256)
k_tr(const float* __restrict__ h, unsigned short* __restrict__ ht){
  __shared__ float tile[64][65];
  const int t = threadIdx.x;
  const int n0 = blockIdx.x * 64;
  #pragma unroll
  for (int s = 0; s < 4; ++s){
    const int r = s*16 + (t>>4);
    const int c = (t&15)*4;
    const float4 v = *(const float4*)(h + (size_t)(n0+r)*F + c);
    tile[r][c] = v.x; tile[r][c+1] = v.y; tile[r][c+2] = v.z; tile[r][c+3] = v.w;
  }
  __syncthreads();
  const int f = t >> 2, jq = t & 3;
  unsigned short buf[16];
  #pragma unroll
  for (int k = 0; k < 16; ++k) buf[k] = f2bf(tile[jq*16 + k][f]);
  *(uint4*)(ht + (size_t)f*N + n0 + jq*16)     = *(uint4*)&buf[0];
  *(uint4*)(ht + (size_t)f*N + n0 + jq*16 + 8) = *(uint4*)&buf[8];
}

// k_scan: exclusive scan of 8192 row totals -> base
extern "C" __global__ void __launch_bounds__(1024)
k_scan(const int* __restrict__ cnt, int* __restrict__ base){
  __shared__ int wsum[16];
  const int t = threadIdx.x, lane = t & 63, w = t >> 6;
  int4 aa = ((const int4*)cnt)[t * 2];
  int4 bb = ((const int4*)cnt)[t * 2 + 1];
  int v[8] = {aa.x, aa.y, aa.z, aa.w, bb.x, bb.y, bb.z, bb.w};
  int local = 0;
  #pragma unroll
  for (int k = 0; k < 8; ++k){ int tmp = v[k]; v[k] = local; local += tmp; }
  int inc = wave_incl_scan_i(local, lane);
  int wexcl = inc - local;
  if (lane == 63) wsum[w] = inc;
  __syncthreads();
  if (t == 0){
    int run = 0;
    #pragma unroll
    for (int k = 0; k < 16; ++k){ int tmp = wsum[k]; wsum[k] = run; run += tmp; }
  }
  __syncthreads();
  const int b0 = wsum[w] + wexcl;
  ((int4*)base)[t * 2]     = make_int4(b0 + v[0], b0 + v[1], b0 + v[2], b0 + v[3]);
  ((int4*)base)[t * 2 + 1] = make_int4(b0 + v[4], b0 + v[5], b0 + v[6], b0 + v[7]);
}

// k_main: 1024 independent blocks = (vid, half). 256 threads, 16 rows x 16 chunks.
// R16/R19 structure + block-major bm (128-B coalesced wave reads) + mask
// rotation one interval ahead (only 2 scalar regs cross MM).
extern "C" __global__ void __launch_bounds__(256, 4)
k_main(const unsigned short* __restrict__ bm, const unsigned short* __restrict__ ccnt,
       const int* __restrict__ base, const unsigned short* __restrict__ ht,
       const float* __restrict__ ssrc, const float* __restrict__ sdst2x,
       float* __restrict__ pnum, float* __restrict__ pden){
  __shared__ __attribute__((aligned(16))) char pt[2][16*ROWSTR]; // 17.5 KB dbuf A-tile
  __shared__ unsigned short ccum[BI][HALFCH];                    // chunk start ranks
  __shared__ int basel[BI];

  const int t = threadIdx.x, w = t >> 6, lane = t & 63;
  const int vid = blockIdx.x >> 1, half = blockIdx.x & 1;
  const int i0 = vid * BI;
  const int ch0 = half * HALFCH;

  if (t < BI) basel[t] = base[i0 + t];
  const int r = t >> 4, g = t & 15;         // produce roles
  // phase 0: per-row within-row rank offsets for my 16 chunks (from ccnt)
  {
    int c = (int)ccnt[(size_t)(i0+r)*NCHUNK + ch0 + g];
    int pre = 0;
    if (half){
      pre = (int)ccnt[(size_t)(i0+r)*NCHUNK + g];
      #pragma unroll
      for (int d = 1; d < 16; d <<= 1) pre += __shfl_xor(pre, d, 16);
    }
    int inc = c;
    #pragma unroll
    for (int d = 1; d < 16; d <<= 1){ int u = __shfl_up(inc, d, 16); if (g >= d) inc += u; }
    ccum[r][g] = (unsigned short)(pre + inc - c);
  }
  __syncthreads();

  const int fr = lane & 15, ks = lane >> 4; // mfma fragment roles
  const int fB = w*16 + fr;
  char* buf0 = pt[0];
  char* buf1 = pt[1];
  const int rowbase = basel[r];
  float dsum = 0.f;
  f32x4 acc = {0.f, 0.f, 0.f, 0.f};
  bf16x8 bregA[8], bregB[8];

  // block-major bm: wave reads 128 B contiguous per chunk
#define BMLD(CC) ((unsigned)bm[((size_t)vid*NCHUNK + ch0 + (CC))*256 + t])

#define PREFETCH(CH, BR) { \
    const unsigned short* hBp = ht + (size_t)fB*N + (CH)*BJ + ks*8; \
    _Pragma("unroll") \
    for (int kk = 0; kk < 8; ++kk) BR[kk] = *(const bf16x8*)(hBp + kk*32); \
    __builtin_amdgcn_sched_barrier(0); \
  }

  // produce (mask passed in — no load at head): dual 8-bit chains, unconditional
  // select-address scatter (active -> real slot, inactive -> dummy slot)
#define PRODUCE(CC, PB, MV) { \
    const unsigned m = (MV); \
    const unsigned mlo = m & 0xffu, mhi = m >> 8; \
    const int clo = __popc(mlo), chi = __popc(mhi); \
    const int c = clo + chi; \
    int inc = c; \
    _Pragma("unroll") \
    for (int d = 1; d < 16; d <<= 1){ int u = __shfl_up(inc, d, 16); if (g >= d) inc += u; } \
    const int qex = inc - c; \
    const int q0row = rowbase + (int)ccum[r][CC]; \
    const float* sdw = sdst2x + (q0row & (N - 1)) + qex; \
    const int ilo = q0row >> 13; \
    const float s_lo = ssrc[ilo]; \
    const float s_hi = ssrc[ilo + 1]; \
    const int krel = ((ilo + 1) << 13) - q0row - qex; \
    char* myrow = (PB) + r*ROWSTR; \
    *(uint4*)(myrow + g*32)      = make_uint4(0,0,0,0); \
    *(uint4*)(myrow + g*32 + 16) = make_uint4(0,0,0,0); \
    float wvlo[8], wvhi[8]; \
    const float* sdh = sdw + clo; \
    _Pragma("unroll") \
    for (int k = 0; k < 8; ++k){ wvlo[k] = sdw[k]; wvhi[k] = sdh[k]; } \
    float dlo = 0.f, dhi = 0.f; \
    unsigned mcl = mlo, mch = mhi; \
    _Pragma("unroll") \
    for (int k = 0; k < 8; ++k){ \
      { \
        const float ss = (k >= krel) ? s_hi : s_lo; \
        float e = ss + wvlo[k]; \
        e = (e > 0.f) ? e : LEAKY * e; \
        const float p = __expf(e); \
        const int pos = __ffs(mcl) - 1; \
        const bool act = (k < clo); \
        dlo += act ? p : 0.f; \
        const int off = act ? (g*32 + pos*2) : (512 + g*2); \
        *(unsigned short*)(myrow + off) = f2bf(p); \
        mcl &= mcl - 1; \
      } \
      { \
        const int kg = clo + k; \
        const float ss = (kg >= krel) ? s_hi : s_lo; \
        float e = ss + wvhi[k]; \
        e = (e > 0.f) ? e : LEAKY * e; \
        const float p = __expf(e); \
        const int pos = __ffs(mch) + 7; \
        const bool act = (k < chi); \
        dhi += act ? p : 0.f; \
        const int off = act ? (g*32 + pos*2) : (512 + g*2); \
        *(unsigned short*)(myrow + off) = f2bf(p); \
        mch &= mch - 1; \
      } \
    } \
    dsum += dlo + dhi; \
  }

#define MM(PB, BR) { \
    const char* aP = (PB) + fr*ROWSTR; \
    __builtin_amdgcn_s_setprio(1); \
    _Pragma("unroll") \
    for (int kk = 0; kk < 8; ++kk){ \
      bf16x8 av = *(const bf16x8*)(aP + kk*64 + ks*16); \
      acc = __builtin_amdgcn_mfma_f32_16x16x32_bf16(av, BR[kk], acc, 0, 0, 0); \
    } \
    __builtin_amdgcn_s_setprio(0); \
  }

  // prologue: masks for chunks 0 and 1 issued; produce chunk 0
  unsigned mCur = BMLD(0);
  unsigned mNxt = BMLD(1);
  PREFETCH(ch0, bregA)
  PRODUCE(0, buf0, mCur)
  __syncthreads();
  for (int cc = 0; cc < HALFCH; cc += 2){
    {
      PREFETCH(ch0 + cc + 1, bregB)
      const unsigned mUse = mNxt;
      if (cc + 2 < HALFCH) mNxt = BMLD(cc + 2);
      PRODUCE(cc + 1, buf1, mUse)
      MM(buf0, bregA)
    }
    __syncthreads();
    if (cc + 2 < HALFCH){
      PREFETCH(ch0 + cc + 2, bregA)
      const unsigned mUse = mNxt;
      if (cc + 3 < HALFCH) mNxt = BMLD(cc + 3);
      PRODUCE(cc + 2, buf0, mUse)
      MM(buf1, bregB)
    } else {
      MM(buf1, bregB)
    }
    __syncthreads();
  }
#undef BMLD
#undef PREFETCH
#undef PRODUCE
#undef MM

  // epilogue: partial denominators (produce roles) + partial numerators (mfma roles)
  #pragma unroll
  for (int d = 8; d > 0; d >>= 1) dsum += __shfl_xor(dsum, d, 16);
  if (g == 0) pden[(size_t)half*N + i0 + r] = dsum;
  #pragma unroll
  for (int reg = 0; reg < 4; ++reg){
    const int il = ks*4 + reg;
    pnum[(size_t)half*N*F + (size_t)(i0 + il)*F + fB] = acc[reg];
  }
}

// k_comb: out = elu((n0+n1)/(d0+d1))
extern "C" __global__ void __launch_bounds__(256)
k_comb(const float* __restrict__ pnum, const float* __restrict__ pden,
       float* __restrict__ out){
  const int idx = blockIdx.x * 256 + threadIdx.x;   // 0 .. N*F-1
  const int i = idx >> 6;
  const float dn = pden[i] + pden[N + i];
  const float nm = pnum[idx] + pnum[(size_t)N*F + idx];
  float v = (dn > 0.f) ? nm / dn : 0.f;
  out[idx] = (v > 0.f) ? v : (__expf(v) - 1.f);
}

extern "C" void kernel_launch(void* const* d_in, const int* in_sizes, int n_in,
                              void* d_out, int out_size, void* d_ws, size_t ws_size,
                              hipStream_t stream){
  const float* x   = (const float*)d_in[0];
  const int*   adj = (const int*)d_in[1];
  const float* ww  = (const float*)d_in[2];
  const float* wb  = (const float*)d_in[3];
  const float* aw  = (const float*)d_in[4];
  const float* ab  = (const float*)d_in[5];
  float* out = (float*)d_out;

  char* ws = (char*)d_ws;
  float*          h      = (float*)(ws);                       // 2 MB
  unsigned short* ht     = (unsigned short*)(ws + (2u<<20));   // 1 MB
  float*          ssrc   = (float*)(ws + (3u<<20));            // 32 KB
  float*          sdst2x = (float*)(ws + (3u<<20) + 32*1024);  // 64 KB
  int*            rowtot = (int*)(ws + (3u<<20) + 96*1024);    // 32 KB
  int*            base   = (int*)(ws + (3u<<20) + 128*1024);   // 32 KB
  unsigned short* ccnt   = (unsigned short*)(ws + (3u<<20) + 160*1024); // 512 KB
  unsigned short* bm     = (unsigned short*)(ws + (4u<<20));   // 8 MB
  float*          pnum   = (float*)(ws + (12u<<20));           // 4 MB
  float*          pden   = (float*)(ws + (16u<<20));           // 64 KB

  k_packh<<<N + N/4, 256, 0, stream>>>(adj, bm, ccnt, rowtot,
                                       x, ww, wb, aw, ab, h, ssrc, sdst2x);
  k_tr  <<<N/64,   256, 0, stream>>>(h, ht);
  k_scan<<<1,     1024, 0, stream>>>(rowtot, base);
  k_main<<<2*(N/BI), 256, 0, stream>>>(bm, ccnt, base, ht, ssrc, sdst2x, pnum, pden);
  k_comb<<<(N*F)/256, 256, 0, stream>>>(pnum, pden, out);
}

// Round 21
// 160.452 us; speedup vs baseline: 1.9917x; 1.0126x over previous
//
#include <hip/hip_runtime.h>
#include <cstdint>
#include <cstddef>

#define N 8192
#define F 64
#define NEMB 128
#define BI 16
#define BJ 256
#define NCHUNK 32
#define HALFCH 16
#define ROWSTR 560
#define LEAKY 0.01f
#define LOG2E 1.44269504f

typedef __attribute__((ext_vector_type(8))) short bf16x8;
typedef __attribute__((ext_vector_type(4))) float f32x4;

__device__ __forceinline__ float wave_reduce_sum_f(float v){
  #pragma unroll
  for (int d = 32; d > 0; d >>= 1) v += __shfl_xor(v, d, 64);
  return v;
}
__device__ __forceinline__ int wave_reduce_sum_i(int v){
  #pragma unroll
  for (int d = 32; d > 0; d >>= 1) v += __shfl_xor(v, d, 64);
  return v;
}
__device__ __forceinline__ int wave_incl_scan_i(int v, int lane){
  #pragma unroll
  for (int d = 1; d < 64; d <<= 1){
    int u = __shfl_up(v, d, 64);
    if (lane >= d) v += u;
  }
  return v;
}
__device__ __forceinline__ unsigned short f2bf(float x){
  union { float f; unsigned u; } v; v.f = x;
  unsigned r = v.u + 0x7fff + ((v.u >> 16) & 1);
  return (unsigned short)(r >> 16);
}

// k_packh: blocks [0,N): adj row -> BLOCK-MAJOR masks bm[vid][ch][(i&15)*16+g]
// + per-row-chunk counts + row totals. blocks [N, N+N/4): h = x@W^T + b;
// ssrc/sdst tables in LOG2 domain (a_bias folded, x log2e).
extern "C" __global__ void __launch_bounds__(256)
k_packh(const int* __restrict__ adj, unsigned short* __restrict__ bm,
        unsigned short* __restrict__ ccnt, int* __restrict__ rowtot,
        const float* __restrict__ x, const float* __restrict__ ww,
        const float* __restrict__ wb, const float* __restrict__ aw,
        const float* __restrict__ abias,
        float* __restrict__ h, float* __restrict__ ssrc, float* __restrict__ sdst2x){
  const int t = threadIdx.x;
  if (blockIdx.x < N){
    const int i = blockIdx.x;
    int total = 0;
    #pragma unroll
    for (int half = 0; half < 2; ++half){
      const int w = half*256 + t;           // word index 0..511
      const int4* p4 = (const int4*)(adj + (size_t)i*N + w*16);
      unsigned m = 0;
      #pragma unroll
      for (int k = 0; k < 4; ++k){
        int4 a = p4[k];
        m |= (unsigned)(a.x>0) << (k*4+0);
        m |= (unsigned)(a.y>0) << (k*4+1);
        m |= (unsigned)(a.z>0) << (k*4+2);
        m |= (unsigned)(a.w>0) << (k*4+3);
      }
      // block-major: [i>>4][w>>4][(i&15)*16 + (w&15)]
      bm[((size_t)(i >> 4)*NCHUNK + (w >> 4))*256 + (i & 15)*16 + (w & 15)] =
          (unsigned short)m;
      const int pc = __popc(m);
      total += pc;
      int cs = pc;
      cs += __shfl_xor(cs, 1, 16);
      cs += __shfl_xor(cs, 2, 16);
      cs += __shfl_xor(cs, 4, 16);
      cs += __shfl_xor(cs, 8, 16);
      if ((t & 15) == 0) ccnt[(size_t)i*NCHUNK + (w>>4)] = (unsigned short)cs;
    }
    total = wave_reduce_sum_i(total);
    __shared__ int ws_[4];
    if ((t & 63) == 0) ws_[t >> 6] = total;
    __syncthreads();
    if (t == 0) rowtot[i] = ws_[0] + ws_[1] + ws_[2] + ws_[3];
  } else {
    const int w = t >> 6, lane = t & 63;
    __shared__ float xs[4][NEMB];
    const int n0 = (blockIdx.x - N) * 4;
    ((float2*)&xs[0][0])[t] = ((const float2*)(x + (size_t)n0 * NEMB))[t];
    __syncthreads();
    const int n = n0 + w;
    const float4* w4 = (const float4*)(ww + (size_t)lane * NEMB);
    const float4* x4 = (const float4*)&xs[w][0];
    float acc = wb[lane];
    #pragma unroll
    for (int k = 0; k < NEMB/4; ++k){
      float4 a = x4[k]; float4 b = w4[k];
      acc = fmaf(a.x, b.x, acc);
      acc = fmaf(a.y, b.y, acc);
      acc = fmaf(a.z, b.z, acc);
      acc = fmaf(a.w, b.w, acc);
    }
    h[(size_t)n * F + lane] = acc;
    float vs = wave_reduce_sum_f(acc * aw[lane]);
    float vd = wave_reduce_sum_f(acc * aw[F + lane]);
    if (lane == 0){
      ssrc[n] = (vs + abias[0]) * LOG2E;    // log2 domain, a_bias folded
      const float vdl = vd * LOG2E;
      sdst2x[n] = vdl; sdst2x[n + N] = vdl;
    }
  }
}

// k_tr: transpose h (fp32 [N][F]) -> ht (bf16 [F][N])
extern "C" __global__ void __launch_bounds__(256)
k_tr(const float* __restrict__ h, unsigned short* __restrict__ ht){
  __shared__ float tile[64][65];
  const int t = threadIdx.x;
  const int n0 = blockIdx.x * 64;
  #pragma unroll
  for (int s = 0; s < 4; ++s){
    const int r = s*16 + (t>>4);
    const int c = (t&15)*4;
    const float4 v = *(const float4*)(h + (size_t)(n0+r)*F + c);
    tile[r][c] = v.x; tile[r][c+1] = v.y; tile[r][c+2] = v.z; tile[r][c+3] = v.w;
  }
  __syncthreads();
  const int f = t >> 2, jq = t & 3;
  unsigned short buf[16];
  #pragma unroll
  for (int k = 0; k < 16; ++k) buf[k] = f2bf(tile[jq*16 + k][f]);
  *(uint4*)(ht + (size_t)f*N + n0 + jq*16)     = *(uint4*)&buf[0];
  *(uint4*)(ht + (size_t)f*N + n0 + jq*16 + 8) = *(uint4*)&buf[8];
}

// k_scan: exclusive scan of 8192 row totals -> base
extern "C" __global__ void __launch_bounds__(1024)
k_scan(const int* __restrict__ cnt, int* __restrict__ base){
  __shared__ int wsum[16];
  const int t = threadIdx.x, lane = t & 63, w = t >> 6;
  int4 aa = ((const int4*)cnt)[t * 2];
  int4 bb = ((const int4*)cnt)[t * 2 + 1];
  int v[8] = {aa.x, aa.y, aa.z, aa.w, bb.x, bb.y, bb.z, bb.w};
  int local = 0;
  #pragma unroll
  for (int k = 0; k < 8; ++k){ int tmp = v[k]; v[k] = local; local += tmp; }
  int inc = wave_incl_scan_i(local, lane);
  int wexcl = inc - local;
  if (lane == 63) wsum[w] = inc;
  __syncthreads();
  if (t == 0){
    int run = 0;
    #pragma unroll
    for (int k = 0; k < 16; ++k){ int tmp = wsum[k]; wsum[k] = run; run += tmp; }
  }
  __syncthreads();
  const int b0 = wsum[w] + wexcl;
  ((int4*)base)[t * 2]     = make_int4(b0 + v[0], b0 + v[1], b0 + v[2], b0 + v[3]);
  ((int4*)base)[t * 2 + 1] = make_int4(b0 + v[4], b0 + v[5], b0 + v[6], b0 + v[7]);
}

// k_main: 1024 independent blocks = (vid, half). 256 threads, 16 rows x 16 chunks.
// R20 structure + log2-domain produce (raw v_exp_f32, fmax-leaky, cheap bf16
// round): ~13 VALU ops/element vs 17.
extern "C" __global__ void __launch_bounds__(256, 4)
k_main(const unsigned short* __restrict__ bm, const unsigned short* __restrict__ ccnt,
       const int* __restrict__ base, const unsigned short* __restrict__ ht,
       const float* __restrict__ ssrc, const float* __restrict__ sdst2x,
       float* __restrict__ pnum, float* __restrict__ pden){
  __shared__ __attribute__((aligned(16))) char pt[2][16*ROWSTR]; // 17.5 KB dbuf A-tile
  __shared__ unsigned short ccum[BI][HALFCH];                    // chunk start ranks
  __shared__ int basel[BI];

  const int t = threadIdx.x, w = t >> 6, lane = t & 63;
  const int vid = blockIdx.x >> 1, half = blockIdx.x & 1;
  const int i0 = vid * BI;
  const int ch0 = half * HALFCH;

  if (t < BI) basel[t] = base[i0 + t];
  const int r = t >> 4, g = t & 15;         // produce roles
  // phase 0: per-row within-row rank offsets for my 16 chunks (from ccnt)
  {
    int c = (int)ccnt[(size_t)(i0+r)*NCHUNK + ch0 + g];
    int pre = 0;
    if (half){
      pre = (int)ccnt[(size_t)(i0+r)*NCHUNK + g];
      #pragma unroll
      for (int d = 1; d < 16; d <<= 1) pre += __shfl_xor(pre, d, 16);
    }
    int inc = c;
    #pragma unroll
    for (int d = 1; d < 16; d <<= 1){ int u = __shfl_up(inc, d, 16); if (g >= d) inc += u; }
    ccum[r][g] = (unsigned short)(pre + inc - c);
  }
  __syncthreads();

  const int fr = lane & 15, ks = lane >> 4; // mfma fragment roles
  const int fB = w*16 + fr;
  char* buf0 = pt[0];
  char* buf1 = pt[1];
  const int rowbase = basel[r];
  float dsum = 0.f;
  f32x4 acc = {0.f, 0.f, 0.f, 0.f};
  bf16x8 bregA[8], bregB[8];

  // block-major bm: wave reads 128 B contiguous per chunk
#define BMLD(CC) ((unsigned)bm[((size_t)vid*NCHUNK + ch0 + (CC))*256 + t])

#define PREFETCH(CH, BR) { \
    const unsigned short* hBp = ht + (size_t)fB*N + (CH)*BJ + ks*8; \
    _Pragma("unroll") \
    for (int kk = 0; kk < 8; ++kk) BR[kk] = *(const bf16x8*)(hBp + kk*32); \
    __builtin_amdgcn_sched_barrier(0); \
  }

  // produce: dual 8-bit chains; log2-domain exp (raw v_exp_f32), fmax-leaky,
  // cheap round-to-nearest bf16; unconditional select-address scatter
#define PRODUCE(CC, PB, MV) { \
    const unsigned m = (MV); \
    const unsigned mlo = m & 0xffu, mhi = m >> 8; \
    const int clo = __popc(mlo), chi = __popc(mhi); \
    const int c = clo + chi; \
    int inc = c; \
    _Pragma("unroll") \
    for (int d = 1; d < 16; d <<= 1){ int u = __shfl_up(inc, d, 16); if (g >= d) inc += u; } \
    const int qex = inc - c; \
    const int q0row = rowbase + (int)ccum[r][CC]; \
    const float* sdw = sdst2x + (q0row & (N - 1)) + qex; \
    const int ilo = q0row >> 13; \
    const float s_lo = ssrc[ilo]; \
    const float s_hi = ssrc[ilo + 1]; \
    const int krel = ((ilo + 1) << 13) - q0row - qex; \
    char* myrow = (PB) + r*ROWSTR; \
    *(uint4*)(myrow + g*32)      = make_uint4(0,0,0,0); \
    *(uint4*)(myrow + g*32 + 16) = make_uint4(0,0,0,0); \
    float wvlo[8], wvhi[8]; \
    const float* sdh = sdw + clo; \
    _Pragma("unroll") \
    for (int k = 0; k < 8; ++k){ wvlo[k] = sdw[k]; wvhi[k] = sdh[k]; } \
    float dlo = 0.f, dhi = 0.f; \
    unsigned mcl = mlo, mch = mhi; \
    _Pragma("unroll") \
    for (int k = 0; k < 8; ++k){ \
      { \
        const float ss = (k >= krel) ? s_hi : s_lo; \
        float e = ss + wvlo[k]; \
        e = fmaxf(e, LEAKY * e); \
        float p; \
        asm("v_exp_f32 %0, %1" : "=v"(p) : "v"(e)); \
        const int pos = __ffs(mcl) - 1; \
        const bool act = (k < clo); \
        dlo += act ? p : 0.f; \
        const int off = act ? (g*32 + pos*2) : (512 + g*2); \
        *(unsigned short*)(myrow + off) = \
            (unsigned short)((__float_as_uint(p) + 0x8000u) >> 16); \
        mcl &= mcl - 1; \
      } \
      { \
        const int kg = clo + k; \
        const float ss = (kg >= krel) ? s_hi : s_lo; \
        float e = ss + wvhi[k]; \
        e = fmaxf(e, LEAKY * e); \
        float p; \
        asm("v_exp_f32 %0, %1" : "=v"(p) : "v"(e)); \
        const int pos = __ffs(mch) + 7; \
        const bool act = (k < chi); \
        dhi += act ? p : 0.f; \
        const int off = act ? (g*32 + pos*2) : (512 + g*2); \
        *(unsigned short*)(myrow + off) = \
            (unsigned short)((__float_as_uint(p) + 0x8000u) >> 16); \
        mch &= mch - 1; \
      } \
    } \
    dsum += dlo + dhi; \
  }

#define MM(PB, BR) { \
    const char* aP = (PB) + fr*ROWSTR; \
    __builtin_amdgcn_s_setprio(1); \
    _Pragma("unroll") \
    for (int kk = 0; kk < 8; ++kk){ \
      bf16x8 av = *(const bf16x8*)(aP + kk*64 + ks*16); \
      acc = __builtin_amdgcn_mfma_f32_16x16x32_bf16(av, BR[kk], acc, 0, 0, 0); \
    } \
    __builtin_amdgcn_s_setprio(0); \
  }

  // prologue: masks for chunks 0 and 1 issued; produce chunk 0
  unsigned mCur = BMLD(0);
  unsigned mNxt = BMLD(1);
  PREFETCH(ch0, bregA)
  PRODUCE(0, buf0, mCur)
  __syncthreads();
  for (int cc = 0; cc < HALFCH; cc += 2){
    {
      PREFETCH(ch0 + cc + 1, bregB)
      const unsigned mUse = mNxt;
      if (cc + 2 < HALFCH) mNxt = BMLD(cc + 2);
      PRODUCE(cc + 1, buf1, mUse)
      MM(buf0, bregA)
    }
    __syncthreads();
    if (cc + 2 < HALFCH){
      PREFETCH(ch0 + cc + 2, bregA)
      const unsigned mUse = mNxt;
      if (cc + 3 < HALFCH) mNxt = BMLD(cc + 3);
      PRODUCE(cc + 2, buf0, mUse)
      MM(buf1, bregB)
    } else {
      MM(buf1, bregB)
    }
    __syncthreads();
  }
#undef BMLD
#undef PREFETCH
#undef PRODUCE
#undef MM

  // epilogue: partial denominators (produce roles) + partial numerators (mfma roles)
  #pragma unroll
  for (int d = 8; d > 0; d >>= 1) dsum += __shfl_xor(dsum, d, 16);
  if (g == 0) pden[(size_t)half*N + i0 + r] = dsum;
  #pragma unroll
  for (int reg = 0; reg < 4; ++reg){
    const int il = ks*4 + reg;
    pnum[(size_t)half*N*F + (size_t)(i0 + il)*F + fB] = acc[reg];
  }
}

// k_comb: out = elu((n0+n1)/(d0+d1))
extern "C" __global__ void __launch_bounds__(256)
k_comb(const float* __restrict__ pnum, const float* __restrict__ pden,
       float* __restrict__ out){
  const int idx = blockIdx.x * 256 + threadIdx.x;   // 0 .. N*F-1
  const int i = idx >> 6;
  const float dn = pden[i] + pden[N + i];
  const float nm = pnum[idx] + pnum[(size_t)N*F + idx];
  float v = (dn > 0.f) ? nm / dn : 0.f;
  out[idx] = (v > 0.f) ? v : (__expf(v) - 1.f);
}

extern "C" void kernel_launch(void* const* d_in, const int* in_sizes, int n_in,
                              void* d_out, int out_size, void* d_ws, size_t ws_size,
                              hipStream_t stream){
  const float* x   = (const float*)d_in[0];
  const int*   adj = (const int*)d_in[1];
  const float* ww  = (const float*)d_in[2];
  const float* wb  = (const float*)d_in[3];
  const float* aw  = (const float*)d_in[4];
  const float* ab  = (const float*)d_in[5];
  float* out = (float*)d_out;

  char* ws = (char*)d_ws;
  float*          h      = (float*)(ws);                       // 2 MB
  unsigned short* ht     = (unsigned short*)(ws + (2u<<20));   // 1 MB
  float*          ssrc   = (float*)(ws + (3u<<20));            // 32 KB
  float*          sdst2x = (float*)(ws + (3u<<20) + 32*1024);  // 64 KB
  int*            rowtot = (int*)(ws + (3u<<20) + 96*1024);    // 32 KB
  int*            base   = (int*)(ws + (3u<<20) + 128*1024);   // 32 KB
  unsigned short* ccnt   = (unsigned short*)(ws + (3u<<20) + 160*1024); // 512 KB
  unsigned short* bm     = (unsigned short*)(ws + (4u<<20));   // 8 MB
  float*          pnum   = (float*)(ws + (12u<<20));           // 4 MB
  float*          pden   = (float*)(ws + (16u<<20));           // 64 KB

  k_packh<<<N + N/4, 256, 0, stream>>>(adj, bm, ccnt, rowtot,
                                       x, ww, wb, aw, ab, h, ssrc, sdst2x);
  k_tr  <<<N/64,   256, 0, stream>>>(h, ht);
  k_scan<<<1,     1024, 0, stream>>>(rowtot, base);
  k_main<<<2*(N/BI), 256, 0, stream>>>(bm, ccnt, base, ht, ssrc, sdst2x, pnum, pden);
  k_comb<<<(N*F)/256, 256, 0, stream>>>(pnum, pden, out);
}